// Round 3
// baseline (168.971 us; speedup 1.0000x reference)
//
#include <hip/hip_runtime.h>

// Aggregation (SAN-style): out[n, g*CW+cc, h, w] =
//   sum_{kh,kw} input[n, g*CW+cc, h+kh-PAD, w+kw-PAD] * weight[n, cc, kh*K+kw, h, w]
// input [16,256,32,32] f32, weight [16,32,49,32,32] f32, out = input shape.
// Memory-bound: ~130 MB traffic -> ~20.6 us floor at 6.3 TB/s.
//
// R2 (resubmit; R2 bench was GPUAcquisitionTimeout — never ran):
// h-split for occupancy. One block per (n, cc, h-half). LDS 27.5 KB,
// 1024 blocks, launch_bounds(256,4) -> 4 blocks/CU = 16 waves/CU (vs 8 in R1).
// Each thread handles 4 of the 8 groups (t>>7 picks the half) -> acc 16 VGPR.

#define KS   7
#define PAD  3
#define HH   32
#define WW   32
#define CW   32   // weight channels
#define GG   8    // share groups = 256/32
#define GH   4    // groups per thread
#define CX   256
#define HB   16   // output rows per block
#define PROW (HB + 2*PAD)   // 22 padded rows
#define PSTR 40             // padded row stride (floats), rows 16B-aligned

__global__ __launch_bounds__(256, 4)
void aggregation_kernel(const float* __restrict__ input,
                        const float* __restrict__ weight,
                        float* __restrict__ out) {
    // 8 channels x 22 rows x 40 floats = 28160 B
    __shared__ float lds[GG * PROW * PSTR];

    const int t   = threadIdx.x;          // 0..255
    const int bid = blockIdx.x;           // 0..1023
    const int hs  = bid & 1;              // h-half
    const int cc  = (bid >> 1) & (CW-1);  // 0..31
    const int n   = bid >> 6;             // 0..15
    const int h0  = hs * HB;

    // ---- 1) zero LDS (borders must be 0) ----
    float4* lz = reinterpret_cast<float4*>(lds);
    #pragma unroll
    for (int i = 0; i < 7; ++i) {
        int idx = t + i * 256;
        if (idx < GG * PROW * PSTR / 4)
            lz[idx] = make_float4(0.f, 0.f, 0.f, 0.f);
    }
    __syncthreads();

    // ---- 2) stage valid rows of the 8 channels {g*CW+cc} ----
    // slots: 8 ch x 22 rows x 8 quads = 1408 float4 loads (clipped rows skip)
    const float* inbase = input + (size_t)n * CX * HH * WW;
    #pragma unroll
    for (int j = 0; j < 6; ++j) {
        int idx = t + j * 256;
        if (idx < GG * PROW * 8) {
            int ch  = idx / (PROW * 8);
            int rem = idx - ch * (PROW * 8);
            int r   = rem >> 3;            // 0..21 lds row
            int q   = rem & 7;             // quad
            int gr  = h0 - PAD + r;        // global row
            if (gr >= 0 && gr < HH) {
                float4 v = *reinterpret_cast<const float4*>(
                    inbase + ((size_t)(ch * CW + cc) * HH + gr) * WW + (q << 2));
                float* dst = &lds[(ch * PROW + r) * PSTR + (q << 2) + PAD];
                dst[0] = v.x; dst[1] = v.y; dst[2] = v.z; dst[3] = v.w;
            }
        }
    }
    __syncthreads();

    // ---- 3) compute: thread owns (h, w0..w0+3) for 4 groups ----
    const int gh  = t >> 7;          // which group-half (0: g0-3, 1: g4-7)
    const int pos = t & 127;
    const int hr  = pos >> 3;        // 0..15 local row
    const int w0  = (pos & 7) << 2;  // 0,4,...,28
    const int h   = h0 + hr;

    float acc[GH][4];
    #pragma unroll
    for (int gi = 0; gi < GH; ++gi)
        #pragma unroll
        for (int p = 0; p < 4; ++p) acc[gi][p] = 0.f;

    const float* wbase = weight
        + ((size_t)n * CW + cc) * (KS * KS) * (HH * WW)
        + h * WW + w0;

    #pragma unroll
    for (int kh = 0; kh < KS; ++kh) {
        float4 wv[KS];
        #pragma unroll
        for (int kw = 0; kw < KS; ++kw)
            wv[kw] = *reinterpret_cast<const float4*>(
                wbase + (size_t)(kh * KS + kw) * (HH * WW));
        const int row = hr + kh;  // lds row for this tap
        #pragma unroll
        for (int gi = 0; gi < GH; ++gi) {
            const int g = gh * GH + gi;
            // lds[g][row][w0 .. w0+11]: 3 aligned ds_read_b128 serve all taps
            const float4* rp = reinterpret_cast<const float4*>(
                &lds[(g * PROW + row) * PSTR + w0]);
            float4 r0 = rp[0], r1 = rp[1], r2 = rp[2];
            float rr[12] = {r0.x, r0.y, r0.z, r0.w,
                            r1.x, r1.y, r1.z, r1.w,
                            r2.x, r2.y, r2.z, r2.w};
            #pragma unroll
            for (int kw = 0; kw < KS; ++kw) {
                acc[gi][0] = fmaf(rr[kw + 0], wv[kw].x, acc[gi][0]);
                acc[gi][1] = fmaf(rr[kw + 1], wv[kw].y, acc[gi][1]);
                acc[gi][2] = fmaf(rr[kw + 2], wv[kw].z, acc[gi][2]);
                acc[gi][3] = fmaf(rr[kw + 3], wv[kw].w, acc[gi][3]);
            }
        }
    }

    // ---- 4) write out: 4 coalesced float4 stores ----
    #pragma unroll
    for (int gi = 0; gi < GH; ++gi) {
        const int g = gh * GH + gi;
        float4 o = make_float4(acc[gi][0], acc[gi][1], acc[gi][2], acc[gi][3]);
        *reinterpret_cast<float4*>(
            out + (((size_t)n * CX + g * CW + cc) * HH + h) * WW + w0) = o;
    }
}

extern "C" void kernel_launch(void* const* d_in, const int* in_sizes, int n_in,
                              void* d_out, int out_size, void* d_ws, size_t ws_size,
                              hipStream_t stream) {
    const float* input  = (const float*)d_in[0];
    const float* weight = (const float*)d_in[1];
    float* out = (float*)d_out;
    // 16 n * 32 cc * 2 h-halves = 1024 blocks, 256 threads
    aggregation_kernel<<<dim3(16 * CW * 2), dim3(256), 0, stream>>>(input, weight, out);
}